// Round 20
// baseline (125.969 us; speedup 1.0000x reference)
//
#include <hip/hip_runtime.h>

// Integrator (scaling & squaring) for vel [16,2,512,512] f32, with logdet-Jacobian.
// ROUND-20: 4 dispatches — streaming init (roofline) + TWO LDS time-tiled TRIPLES
// + streaming FINAL. (R19 lesson: fusing init into the tile pipeline is VALU-
// amplified 3x — keep init streaming; fuse only step-shaped work.)
//   INIT : records1=(disp1, ldjac0), streaming, corner-select from registers.
//   T1   : K2+K3+K4, reaches (2,2,2): ext 44^2 -> 40^2 -> 36^2 -> core 32^2.
//   T2   : K5+K6+K7, reaches (2,3,4): ext 50^2 -> 46^2 -> 40^2 -> core 32^2.
//   FINAL: ldjac7 from streamed disp7 + planar f32 output.
// All reaches HW-validated in R17 (pairs used the same per-step values).
// Records rec_k=(disp_k.y, disp_k.x, ldjac_{k-1}, 0) f16x4; decoupled schedule.
// M2 aliases IN inside triples (IN dead after phase 1; no race: phase 2 reads
// only M1, writes only M2, separated by barriers).
// Rotation: init->ws, T1: ws->d_out(raw), T2: d_out->ws, FINAL: ws->d_out planar.

#define NB 16
#define HH 512
#define WW 512
#define HW (HH * WW)
#define TOT (NB * HW)
#define EPS 0.0078125f
#define DISP_ELEMS (NB * 2 * HW)
#define SC (512.0f / 511.0f)

typedef _Float16 f16;
typedef _Float16 f16x4 __attribute__((ext_vector_type(4)));

struct SampC {
    int yc0, xc0, yc1, xc1;   // clamped corner coords (global)
    float w00, w01, w10, w11; // bilinear weights, OOB folded to 0
};

__device__ __forceinline__ SampC make_sampc(float sy, float sx) {
    float fy = floorf(sy), fx = floorf(sx);
    float wy = sy - fy, wx = sx - fx;
    int y0 = (int)fy, x0 = (int)fx;
    int y1 = y0 + 1, x1 = x0 + 1;
    bool xv0 = (unsigned)x0 < (unsigned)WW;
    bool xv1 = (unsigned)x1 < (unsigned)WW;
    bool yv0 = (unsigned)y0 < (unsigned)HH;
    bool yv1 = (unsigned)y1 < (unsigned)HH;
    SampC s;
    s.xc0 = min(max(x0, 0), WW - 1); s.xc1 = min(max(x1, 0), WW - 1);
    s.yc0 = min(max(y0, 0), HH - 1); s.yc1 = min(max(y1, 0), HH - 1);
    float omwx = 1.0f - wx, omwy = 1.0f - wy;
    s.w00 = (xv0 && yv0) ? omwx * omwy : 0.0f;
    s.w01 = (xv1 && yv0) ? wx * omwy   : 0.0f;
    s.w10 = (xv0 && yv1) ? omwx * wy   : 0.0f;
    s.w11 = (xv1 && yv1) ? wx * wy     : 0.0f;
    return s;
}

__device__ __forceinline__ f16x4 step_rec(f16x4 rv, f16x4 g00, f16x4 g01,
                                          f16x4 g10, f16x4 g11, const SampC& s) {
    float d0 = (float)rv.x, d1 = (float)rv.y, l = (float)rv.z;
    float nd0 = d0 + s.w00 * (float)g00.x + s.w01 * (float)g01.x
                   + s.w10 * (float)g10.x + s.w11 * (float)g11.x;
    float nd1 = d1 + s.w00 * (float)g00.y + s.w01 * (float)g01.y
                   + s.w10 * (float)g10.y + s.w11 * (float)g11.y;
    float nl  = l  + s.w00 * (float)g00.z + s.w01 * (float)g01.z
                   + s.w10 * (float)g10.z + s.w11 * (float)g11.z;
    f16x4 w; w.x = (f16)nd0; w.y = (f16)nd1; w.z = (f16)nl; w.w = (f16)0.0f;
    return w;
}

__device__ __forceinline__ float rnd16(float v) { return (float)(f16)v; }

// block -> (img, tile origin); XCD-pinned: XCD c owns images {2c, 2c+1}.
__device__ __forceinline__ void tile_map(int& img, int& ty0, int& tx0) {
    int bidx = blockIdx.x;
    int xcd = bidx & 7, sub = bidx >> 3;       // sub in [0,512)
    img = 2 * xcd + (sub >= 256 ? 1 : 0);
    int tile = sub & 255;
    tx0 = (tile & 15) << 5;
    ty0 = (tile >> 4) << 5;
}

// XCD-remapped flat index for streaming kernels (16384 blocks).
__device__ __forceinline__ int remap_idx() {
    int bid = blockIdx.x;
    int task = ((bid & 7) << 11) | (bid >> 3);
    return task * 256 + threadIdx.x;
}

// ---------------- INIT (streaming, R15/R17-validated) ----------------
// records1 = (disp1, ldjac0); K1 corners selected from in-register 3x3 window
// (static-index cndmask chains; |eps*v| <= ~0.05 px so corners are in-window).
__global__ void __launch_bounds__(256) init_fused(const float* __restrict__ vel,
                                                  f16x4* __restrict__ rdst) {
    int idx = remap_idx();
    int n = idx >> 18;
    int rem = idx & (HW - 1);
    int y = rem >> 9, x = rem & (WW - 1);

    const float* v0 = vel + (size_t)n * 2 * HW;
    const float* v1 = v0 + HW;

    int ym = max(y - 1, 0), yp = min(y + 1, HH - 1);
    int xm = max(x - 1, 0), xp = min(x + 1, WW - 1);
    int r0 = ym * WW, r1 = y * WW, r2 = yp * WW;

    float A00 = v0[r0 + xm], A01 = v0[r0 + x], A02 = v0[r0 + xp];
    float A10 = v0[r1 + xm], A11 = v0[r1 + x], A12 = v0[r1 + xp];
    float A20 = v0[r2 + xm], A21 = v0[r2 + x], A22 = v0[r2 + xp];
    float B00 = v1[r0 + xm], B01 = v1[r0 + x], B02 = v1[r0 + xp];
    float B10 = v1[r1 + xm], B11 = v1[r1 + x], B12 = v1[r1 + xp];
    float B20 = v1[r2 + xm], B21 = v1[r2 + x], B22 = v1[r2 + xp];

    float a = 0.125f * ((A20 + 2.0f * A21 + A22) - (A00 + 2.0f * A01 + A02));
    float b = 0.125f * ((A02 + 2.0f * A12 + A22) - (A00 + 2.0f * A10 + A20));
    float c = 0.125f * ((B20 + 2.0f * B21 + B22) - (B00 + 2.0f * B01 + B02));
    float d = 0.125f * ((B02 + 2.0f * B12 + B22) - (B00 + 2.0f * B10 + B20));

    float xa = a, xb = b, xc = c, xd = d;
    float ld = EPS * (xa + xd);
    float na = xa * a + xb * c, nb = xa * b + xb * d;
    float nc = xc * a + xd * c, nd = xc * b + xd * d;
    xa = na; xb = nb; xc = nc; xd = nd;
    ld -= (EPS * EPS) * (xa + xd) * 0.5f;
    na = xa * a + xb * c; nb = xa * b + xb * d;
    nc = xc * a + xd * c; nd = xc * b + xd * d;
    xa = na; xb = nb; xc = nc; xd = nd;
    ld += (EPS * EPS * EPS) * (xa + xd) * (1.0f / 3.0f);
    na = xa * a + xb * c;
    nd = xc * b + xd * d;
    ld -= (EPS * EPS * EPS * EPS) * (na + nd) * 0.25f;

    float d0 = rnd16(EPS * A11);
    float d1 = rnd16(EPS * B11);

    float sy = fmaf((float)y + d0, SC, -0.5f);
    float sx = fmaf((float)x + d1, SC, -0.5f);
    SampC s = make_sampc(sy, sx);

    bool rlo = (sy < (float)y);
    bool clo = (sx < (float)x);

    float Ar0c0 = rlo ? A00 : A10, Ar0c1 = rlo ? A01 : A11, Ar0c2 = rlo ? A02 : A12;
    float Ar1c0 = rlo ? A10 : A20, Ar1c1 = rlo ? A11 : A21, Ar1c2 = rlo ? A12 : A22;
    float Br0c0 = rlo ? B00 : B10, Br0c1 = rlo ? B01 : B11, Br0c2 = rlo ? B02 : B12;
    float Br1c0 = rlo ? B10 : B20, Br1c1 = rlo ? B11 : B21, Br1c2 = rlo ? B12 : B22;

    float g00x = rnd16(EPS * (clo ? Ar0c0 : Ar0c1));
    float g01x = rnd16(EPS * (clo ? Ar0c1 : Ar0c2));
    float g10x = rnd16(EPS * (clo ? Ar1c0 : Ar1c1));
    float g11x = rnd16(EPS * (clo ? Ar1c1 : Ar1c2));
    float g00y = rnd16(EPS * (clo ? Br0c0 : Br0c1));
    float g01y = rnd16(EPS * (clo ? Br0c1 : Br0c2));
    float g10y = rnd16(EPS * (clo ? Br1c0 : Br1c1));
    float g11y = rnd16(EPS * (clo ? Br1c1 : Br1c2));

    float nd0 = d0 + s.w00 * g00x + s.w01 * g01x + s.w10 * g10x + s.w11 * g11x;
    float nd1 = d1 + s.w00 * g00y + s.w01 * g01y + s.w10 * g10y + s.w11 * g11y;

    f16x4 rec;
    rec.x = (f16)nd0; rec.y = (f16)nd1; rec.z = (f16)ld; rec.w = (f16)0.0f;
    rdst[(size_t)n * HW + rem] = rec;
}

// ---------------- TRIPLE: three decoupled steps via LDS time-tiling ----------------
// Core 32x32. R1/R2/R3 = per-step gather reaches. IN ext -> M1 -> M2(aliases IN) -> global.
template <int R1, int R2, int R3>
__global__ void __launch_bounds__(256, 4) step_triple(const f16x4* __restrict__ rsrc,
                                                      f16x4* __restrict__ rdst) {
    constexpr int M2d = 32 + 2 * R3;
    constexpr int M1d = 32 + 2 * (R2 + R3);
    constexpr int Ed  = 32 + 2 * (R1 + R2 + R3);
    __shared__ __align__(16) f16x4 IN[Ed][Ed + 1];
    __shared__ __align__(16) f16x4 M1[M1d][M1d + 1];
    f16x4 (*M2)[M2d + 1] = (f16x4 (*)[M2d + 1])&IN[0][0];   // IN dead after phase 1

    int img, ty0, tx0;
    tile_map(img, ty0, tx0);
    int t = threadIdx.x;
    const f16x4* rp = rsrc + (size_t)img * HW;

    // phase 0: load ext tile (replicate-clamped)
    for (int i = t; i < Ed * Ed; i += 256) {
        int ey = i / Ed, ex = i - ey * Ed;
        int gy = min(max(ty0 - (R1 + R2 + R3) + ey, 0), HH - 1);
        int gx = min(max(tx0 - (R1 + R2 + R3) + ex, 0), WW - 1);
        IN[ey][ex] = rp[gy * WW + gx];
    }
    __syncthreads();

    // phase 1: step a on core+(R2+R3), gathers reach R1 in IN
    {
        const int oy = ty0 - (R1 + R2 + R3), ox = tx0 - (R1 + R2 + R3);
        for (int i = t; i < M1d * M1d; i += 256) {
            int my = i / M1d, mx = i - my * M1d;
            int qy = ty0 - (R2 + R3) + my, qx = tx0 - (R2 + R3) + mx;
            f16x4 rv = IN[my + R1][mx + R1];
            float sy = fmaf((float)qy + (float)rv.x, SC, -0.5f);
            float sx = fmaf((float)qx + (float)rv.y, SC, -0.5f);
            SampC s = make_sampc(sy, sx);
            f16x4 g00 = IN[s.yc0 - oy][s.xc0 - ox];
            f16x4 g01 = IN[s.yc0 - oy][s.xc1 - ox];
            f16x4 g10 = IN[s.yc1 - oy][s.xc0 - ox];
            f16x4 g11 = IN[s.yc1 - oy][s.xc1 - ox];
            M1[my][mx] = step_rec(rv, g00, g01, g10, g11, s);
        }
    }
    __syncthreads();   // IN dead; M2 may overwrite it

    // phase 2: step b on core+R3, gathers reach R2 in M1, writes M2 (aliases IN)
    {
        const int oy = ty0 - (R2 + R3), ox = tx0 - (R2 + R3);
        for (int i = t; i < M2d * M2d; i += 256) {
            int my = i / M2d, mx = i - my * M2d;
            int qy = ty0 - R3 + my, qx = tx0 - R3 + mx;
            f16x4 rv = M1[my + R2][mx + R2];
            float sy = fmaf((float)qy + (float)rv.x, SC, -0.5f);
            float sx = fmaf((float)qx + (float)rv.y, SC, -0.5f);
            SampC s = make_sampc(sy, sx);
            f16x4 g00 = M1[s.yc0 - oy][s.xc0 - ox];
            f16x4 g01 = M1[s.yc0 - oy][s.xc1 - ox];
            f16x4 g10 = M1[s.yc1 - oy][s.xc0 - ox];
            f16x4 g11 = M1[s.yc1 - oy][s.xc1 - ox];
            M2[my][mx] = step_rec(rv, g00, g01, g10, g11, s);
        }
    }
    __syncthreads();

    // phase 3: step c on core, gathers reach R3 in M2, write global
    {
        const int oy = ty0 - R3, ox = tx0 - R3;
        f16x4* wp = rdst + (size_t)img * HW;
        for (int i = t; i < 1024; i += 256) {
            int cy = i >> 5, cx = i & 31;
            int qy = ty0 + cy, qx = tx0 + cx;
            f16x4 rv = M2[cy + R3][cx + R3];
            float sy = fmaf((float)qy + (float)rv.x, SC, -0.5f);
            float sx = fmaf((float)qx + (float)rv.y, SC, -0.5f);
            SampC s = make_sampc(sy, sx);
            f16x4 g00 = M2[s.yc0 - oy][s.xc0 - ox];
            f16x4 g01 = M2[s.yc0 - oy][s.xc1 - ox];
            f16x4 g10 = M2[s.yc1 - oy][s.xc0 - ox];
            f16x4 g11 = M2[s.yc1 - oy][s.xc1 - ox];
            wp[qy * WW + qx] = step_rec(rv, g00, g01, g10, g11, s);
        }
    }
}

// ---------------- FINAL: streaming ldjac7 + planar f32 output ----------------
__global__ void __launch_bounds__(256) step_final(const f16x4* __restrict__ rsrc,
                                                  float* __restrict__ doutp,
                                                  float* __restrict__ loutp) {
    int idx = remap_idx();
    int n = idx >> 18;
    int rem = idx & (HW - 1);
    int y = rem >> 9, x = rem & (WW - 1);

    const f16x4* rp = rsrc + (size_t)n * HW;

    f16x4 rv = rp[rem];
    float d0 = (float)rv.x, d1 = (float)rv.y, l = (float)rv.z;

    float sy = fmaf((float)y + d0, SC, -0.5f);
    float sx = fmaf((float)x + d1, SC, -0.5f);
    SampC s = make_sampc(sy, sx);

    f16x4 g00 = rp[s.yc0 * WW + s.xc0], g01 = rp[s.yc0 * WW + s.xc1];
    f16x4 g10 = rp[s.yc1 * WW + s.xc0], g11 = rp[s.yc1 * WW + s.xc1];

    float nl = l + s.w00 * (float)g00.z + s.w01 * (float)g01.z
                 + s.w10 * (float)g10.z + s.w11 * (float)g11.z;

    float* pd = doutp + (size_t)n * 2 * HW;
    pd[rem]      = d0;
    pd[HW + rem] = d1;
    loutp[(size_t)n * HW + rem] = nl;
}

extern "C" void kernel_launch(void* const* d_in, const int* in_sizes, int n_in,
                              void* d_out, int out_size, void* d_ws, size_t ws_size,
                              hipStream_t stream) {
    const float* vel = (const float*)d_in[0];
    float* out = (float*)d_out;

    f16x4* rWS  = (f16x4*)d_ws;    // 32MB record buffer in ws
    f16x4* rOUT = (f16x4*)d_out;   // 32MB record buffer in d_out raw bytes

    dim3 block(256), gridT(4096), gridS(TOT / 256);

    // INIT: vel -> records1 (ws)
    init_fused<<<gridS, block, 0, stream>>>(vel, rWS);
    // T1 = K2+K3+K4, reaches (2,2,2): records1 (ws) -> records4 (d_out raw)
    step_triple<2, 2, 2><<<gridT, block, 0, stream>>>(rWS, rOUT);
    // T2 = K5+K6+K7, reaches (2,3,4): records4 (d_out raw) -> records7 (ws)
    step_triple<2, 3, 4><<<gridT, block, 0, stream>>>(rOUT, rWS);
    // FINAL: records7 (ws) -> planar f32 d_out (overwrites dead records4)
    step_final<<<gridS, block, 0, stream>>>(rWS, out, out + DISP_ELEMS);
}

// Round 21
// 125.674 us; speedup vs baseline: 1.0023x; 1.0023x over previous
//
#include <hip/hip_runtime.h>

// Integrator (scaling & squaring) for vel [16,2,512,512] f32, with logdet-Jacobian.
// ROUND-20: 4 dispatches — streaming init (roofline) + TWO LDS time-tiled TRIPLES
// + streaming FINAL. (R19 lesson: fusing init into the tile pipeline is VALU-
// amplified 3x — keep init streaming; fuse only step-shaped work.)
//   INIT : records1=(disp1, ldjac0), streaming, corner-select from registers.
//   T1   : K2+K3+K4, reaches (2,2,2): ext 44^2 -> 40^2 -> 36^2 -> core 32^2.
//   T2   : K5+K6+K7, reaches (2,3,4): ext 50^2 -> 46^2 -> 40^2 -> core 32^2.
//   FINAL: ldjac7 from streamed disp7 + planar f32 output.
// All reaches HW-validated in R17 (pairs used the same per-step values).
// Records rec_k=(disp_k.y, disp_k.x, ldjac_{k-1}, 0) f16x4; decoupled schedule.
// M2 aliases IN inside triples (IN dead after phase 1; no race: phase 2 reads
// only M1, writes only M2, separated by barriers).
// Rotation: init->ws, T1: ws->d_out(raw), T2: d_out->ws, FINAL: ws->d_out planar.

#define NB 16
#define HH 512
#define WW 512
#define HW (HH * WW)
#define TOT (NB * HW)
#define EPS 0.0078125f
#define DISP_ELEMS (NB * 2 * HW)
#define SC (512.0f / 511.0f)

typedef _Float16 f16;
typedef _Float16 f16x4 __attribute__((ext_vector_type(4)));

struct SampC {
    int yc0, xc0, yc1, xc1;   // clamped corner coords (global)
    float w00, w01, w10, w11; // bilinear weights, OOB folded to 0
};

__device__ __forceinline__ SampC make_sampc(float sy, float sx) {
    float fy = floorf(sy), fx = floorf(sx);
    float wy = sy - fy, wx = sx - fx;
    int y0 = (int)fy, x0 = (int)fx;
    int y1 = y0 + 1, x1 = x0 + 1;
    bool xv0 = (unsigned)x0 < (unsigned)WW;
    bool xv1 = (unsigned)x1 < (unsigned)WW;
    bool yv0 = (unsigned)y0 < (unsigned)HH;
    bool yv1 = (unsigned)y1 < (unsigned)HH;
    SampC s;
    s.xc0 = min(max(x0, 0), WW - 1); s.xc1 = min(max(x1, 0), WW - 1);
    s.yc0 = min(max(y0, 0), HH - 1); s.yc1 = min(max(y1, 0), HH - 1);
    float omwx = 1.0f - wx, omwy = 1.0f - wy;
    s.w00 = (xv0 && yv0) ? omwx * omwy : 0.0f;
    s.w01 = (xv1 && yv0) ? wx * omwy   : 0.0f;
    s.w10 = (xv0 && yv1) ? omwx * wy   : 0.0f;
    s.w11 = (xv1 && yv1) ? wx * wy     : 0.0f;
    return s;
}

__device__ __forceinline__ f16x4 step_rec(f16x4 rv, f16x4 g00, f16x4 g01,
                                          f16x4 g10, f16x4 g11, const SampC& s) {
    float d0 = (float)rv.x, d1 = (float)rv.y, l = (float)rv.z;
    float nd0 = d0 + s.w00 * (float)g00.x + s.w01 * (float)g01.x
                   + s.w10 * (float)g10.x + s.w11 * (float)g11.x;
    float nd1 = d1 + s.w00 * (float)g00.y + s.w01 * (float)g01.y
                   + s.w10 * (float)g10.y + s.w11 * (float)g11.y;
    float nl  = l  + s.w00 * (float)g00.z + s.w01 * (float)g01.z
                   + s.w10 * (float)g10.z + s.w11 * (float)g11.z;
    f16x4 w; w.x = (f16)nd0; w.y = (f16)nd1; w.z = (f16)nl; w.w = (f16)0.0f;
    return w;
}

__device__ __forceinline__ float rnd16(float v) { return (float)(f16)v; }

// block -> (img, tile origin); XCD-pinned: XCD c owns images {2c, 2c+1}.
__device__ __forceinline__ void tile_map(int& img, int& ty0, int& tx0) {
    int bidx = blockIdx.x;
    int xcd = bidx & 7, sub = bidx >> 3;       // sub in [0,512)
    img = 2 * xcd + (sub >= 256 ? 1 : 0);
    int tile = sub & 255;
    tx0 = (tile & 15) << 5;
    ty0 = (tile >> 4) << 5;
}

// XCD-remapped flat index for streaming kernels (16384 blocks).
__device__ __forceinline__ int remap_idx() {
    int bid = blockIdx.x;
    int task = ((bid & 7) << 11) | (bid >> 3);
    return task * 256 + threadIdx.x;
}

// ---------------- INIT (streaming, R15/R17-validated) ----------------
// records1 = (disp1, ldjac0); K1 corners selected from in-register 3x3 window
// (static-index cndmask chains; |eps*v| <= ~0.05 px so corners are in-window).
__global__ void __launch_bounds__(256) init_fused(const float* __restrict__ vel,
                                                  f16x4* __restrict__ rdst) {
    int idx = remap_idx();
    int n = idx >> 18;
    int rem = idx & (HW - 1);
    int y = rem >> 9, x = rem & (WW - 1);

    const float* v0 = vel + (size_t)n * 2 * HW;
    const float* v1 = v0 + HW;

    int ym = max(y - 1, 0), yp = min(y + 1, HH - 1);
    int xm = max(x - 1, 0), xp = min(x + 1, WW - 1);
    int r0 = ym * WW, r1 = y * WW, r2 = yp * WW;

    float A00 = v0[r0 + xm], A01 = v0[r0 + x], A02 = v0[r0 + xp];
    float A10 = v0[r1 + xm], A11 = v0[r1 + x], A12 = v0[r1 + xp];
    float A20 = v0[r2 + xm], A21 = v0[r2 + x], A22 = v0[r2 + xp];
    float B00 = v1[r0 + xm], B01 = v1[r0 + x], B02 = v1[r0 + xp];
    float B10 = v1[r1 + xm], B11 = v1[r1 + x], B12 = v1[r1 + xp];
    float B20 = v1[r2 + xm], B21 = v1[r2 + x], B22 = v1[r2 + xp];

    float a = 0.125f * ((A20 + 2.0f * A21 + A22) - (A00 + 2.0f * A01 + A02));
    float b = 0.125f * ((A02 + 2.0f * A12 + A22) - (A00 + 2.0f * A10 + A20));
    float c = 0.125f * ((B20 + 2.0f * B21 + B22) - (B00 + 2.0f * B01 + B02));
    float d = 0.125f * ((B02 + 2.0f * B12 + B22) - (B00 + 2.0f * B10 + B20));

    float xa = a, xb = b, xc = c, xd = d;
    float ld = EPS * (xa + xd);
    float na = xa * a + xb * c, nb = xa * b + xb * d;
    float nc = xc * a + xd * c, nd = xc * b + xd * d;
    xa = na; xb = nb; xc = nc; xd = nd;
    ld -= (EPS * EPS) * (xa + xd) * 0.5f;
    na = xa * a + xb * c; nb = xa * b + xb * d;
    nc = xc * a + xd * c; nd = xc * b + xd * d;
    xa = na; xb = nb; xc = nc; xd = nd;
    ld += (EPS * EPS * EPS) * (xa + xd) * (1.0f / 3.0f);
    na = xa * a + xb * c;
    nd = xc * b + xd * d;
    ld -= (EPS * EPS * EPS * EPS) * (na + nd) * 0.25f;

    float d0 = rnd16(EPS * A11);
    float d1 = rnd16(EPS * B11);

    float sy = fmaf((float)y + d0, SC, -0.5f);
    float sx = fmaf((float)x + d1, SC, -0.5f);
    SampC s = make_sampc(sy, sx);

    bool rlo = (sy < (float)y);
    bool clo = (sx < (float)x);

    float Ar0c0 = rlo ? A00 : A10, Ar0c1 = rlo ? A01 : A11, Ar0c2 = rlo ? A02 : A12;
    float Ar1c0 = rlo ? A10 : A20, Ar1c1 = rlo ? A11 : A21, Ar1c2 = rlo ? A12 : A22;
    float Br0c0 = rlo ? B00 : B10, Br0c1 = rlo ? B01 : B11, Br0c2 = rlo ? B02 : B12;
    float Br1c0 = rlo ? B10 : B20, Br1c1 = rlo ? B11 : B21, Br1c2 = rlo ? B12 : B22;

    float g00x = rnd16(EPS * (clo ? Ar0c0 : Ar0c1));
    float g01x = rnd16(EPS * (clo ? Ar0c1 : Ar0c2));
    float g10x = rnd16(EPS * (clo ? Ar1c0 : Ar1c1));
    float g11x = rnd16(EPS * (clo ? Ar1c1 : Ar1c2));
    float g00y = rnd16(EPS * (clo ? Br0c0 : Br0c1));
    float g01y = rnd16(EPS * (clo ? Br0c1 : Br0c2));
    float g10y = rnd16(EPS * (clo ? Br1c0 : Br1c1));
    float g11y = rnd16(EPS * (clo ? Br1c1 : Br1c2));

    float nd0 = d0 + s.w00 * g00x + s.w01 * g01x + s.w10 * g10x + s.w11 * g11x;
    float nd1 = d1 + s.w00 * g00y + s.w01 * g01y + s.w10 * g10y + s.w11 * g11y;

    f16x4 rec;
    rec.x = (f16)nd0; rec.y = (f16)nd1; rec.z = (f16)ld; rec.w = (f16)0.0f;
    rdst[(size_t)n * HW + rem] = rec;
}

// ---------------- TRIPLE: three decoupled steps via LDS time-tiling ----------------
// Core 32x32. R1/R2/R3 = per-step gather reaches. IN ext -> M1 -> M2(aliases IN) -> global.
template <int R1, int R2, int R3>
__global__ void __launch_bounds__(256, 4) step_triple(const f16x4* __restrict__ rsrc,
                                                      f16x4* __restrict__ rdst) {
    constexpr int M2d = 32 + 2 * R3;
    constexpr int M1d = 32 + 2 * (R2 + R3);
    constexpr int Ed  = 32 + 2 * (R1 + R2 + R3);
    __shared__ __align__(16) f16x4 IN[Ed][Ed + 1];
    __shared__ __align__(16) f16x4 M1[M1d][M1d + 1];
    f16x4 (*M2)[M2d + 1] = (f16x4 (*)[M2d + 1])&IN[0][0];   // IN dead after phase 1

    int img, ty0, tx0;
    tile_map(img, ty0, tx0);
    int t = threadIdx.x;
    const f16x4* rp = rsrc + (size_t)img * HW;

    // phase 0: load ext tile (replicate-clamped)
    for (int i = t; i < Ed * Ed; i += 256) {
        int ey = i / Ed, ex = i - ey * Ed;
        int gy = min(max(ty0 - (R1 + R2 + R3) + ey, 0), HH - 1);
        int gx = min(max(tx0 - (R1 + R2 + R3) + ex, 0), WW - 1);
        IN[ey][ex] = rp[gy * WW + gx];
    }
    __syncthreads();

    // phase 1: step a on core+(R2+R3), gathers reach R1 in IN
    {
        const int oy = ty0 - (R1 + R2 + R3), ox = tx0 - (R1 + R2 + R3);
        for (int i = t; i < M1d * M1d; i += 256) {
            int my = i / M1d, mx = i - my * M1d;
            int qy = ty0 - (R2 + R3) + my, qx = tx0 - (R2 + R3) + mx;
            f16x4 rv = IN[my + R1][mx + R1];
            float sy = fmaf((float)qy + (float)rv.x, SC, -0.5f);
            float sx = fmaf((float)qx + (float)rv.y, SC, -0.5f);
            SampC s = make_sampc(sy, sx);
            f16x4 g00 = IN[s.yc0 - oy][s.xc0 - ox];
            f16x4 g01 = IN[s.yc0 - oy][s.xc1 - ox];
            f16x4 g10 = IN[s.yc1 - oy][s.xc0 - ox];
            f16x4 g11 = IN[s.yc1 - oy][s.xc1 - ox];
            M1[my][mx] = step_rec(rv, g00, g01, g10, g11, s);
        }
    }
    __syncthreads();   // IN dead; M2 may overwrite it

    // phase 2: step b on core+R3, gathers reach R2 in M1, writes M2 (aliases IN)
    {
        const int oy = ty0 - (R2 + R3), ox = tx0 - (R2 + R3);
        for (int i = t; i < M2d * M2d; i += 256) {
            int my = i / M2d, mx = i - my * M2d;
            int qy = ty0 - R3 + my, qx = tx0 - R3 + mx;
            f16x4 rv = M1[my + R2][mx + R2];
            float sy = fmaf((float)qy + (float)rv.x, SC, -0.5f);
            float sx = fmaf((float)qx + (float)rv.y, SC, -0.5f);
            SampC s = make_sampc(sy, sx);
            f16x4 g00 = M1[s.yc0 - oy][s.xc0 - ox];
            f16x4 g01 = M1[s.yc0 - oy][s.xc1 - ox];
            f16x4 g10 = M1[s.yc1 - oy][s.xc0 - ox];
            f16x4 g11 = M1[s.yc1 - oy][s.xc1 - ox];
            M2[my][mx] = step_rec(rv, g00, g01, g10, g11, s);
        }
    }
    __syncthreads();

    // phase 3: step c on core, gathers reach R3 in M2, write global
    {
        const int oy = ty0 - R3, ox = tx0 - R3;
        f16x4* wp = rdst + (size_t)img * HW;
        for (int i = t; i < 1024; i += 256) {
            int cy = i >> 5, cx = i & 31;
            int qy = ty0 + cy, qx = tx0 + cx;
            f16x4 rv = M2[cy + R3][cx + R3];
            float sy = fmaf((float)qy + (float)rv.x, SC, -0.5f);
            float sx = fmaf((float)qx + (float)rv.y, SC, -0.5f);
            SampC s = make_sampc(sy, sx);
            f16x4 g00 = M2[s.yc0 - oy][s.xc0 - ox];
            f16x4 g01 = M2[s.yc0 - oy][s.xc1 - ox];
            f16x4 g10 = M2[s.yc1 - oy][s.xc0 - ox];
            f16x4 g11 = M2[s.yc1 - oy][s.xc1 - ox];
            wp[qy * WW + qx] = step_rec(rv, g00, g01, g10, g11, s);
        }
    }
}

// ---------------- FINAL: streaming ldjac7 + planar f32 output ----------------
__global__ void __launch_bounds__(256) step_final(const f16x4* __restrict__ rsrc,
                                                  float* __restrict__ doutp,
                                                  float* __restrict__ loutp) {
    int idx = remap_idx();
    int n = idx >> 18;
    int rem = idx & (HW - 1);
    int y = rem >> 9, x = rem & (WW - 1);

    const f16x4* rp = rsrc + (size_t)n * HW;

    f16x4 rv = rp[rem];
    float d0 = (float)rv.x, d1 = (float)rv.y, l = (float)rv.z;

    float sy = fmaf((float)y + d0, SC, -0.5f);
    float sx = fmaf((float)x + d1, SC, -0.5f);
    SampC s = make_sampc(sy, sx);

    f16x4 g00 = rp[s.yc0 * WW + s.xc0], g01 = rp[s.yc0 * WW + s.xc1];
    f16x4 g10 = rp[s.yc1 * WW + s.xc0], g11 = rp[s.yc1 * WW + s.xc1];

    float nl = l + s.w00 * (float)g00.z + s.w01 * (float)g01.z
                 + s.w10 * (float)g10.z + s.w11 * (float)g11.z;

    float* pd = doutp + (size_t)n * 2 * HW;
    pd[rem]      = d0;
    pd[HW + rem] = d1;
    loutp[(size_t)n * HW + rem] = nl;
}

extern "C" void kernel_launch(void* const* d_in, const int* in_sizes, int n_in,
                              void* d_out, int out_size, void* d_ws, size_t ws_size,
                              hipStream_t stream) {
    const float* vel = (const float*)d_in[0];
    float* out = (float*)d_out;

    f16x4* rWS  = (f16x4*)d_ws;    // 32MB record buffer in ws
    f16x4* rOUT = (f16x4*)d_out;   // 32MB record buffer in d_out raw bytes

    dim3 block(256), gridT(4096), gridS(TOT / 256);

    // INIT: vel -> records1 (ws)
    init_fused<<<gridS, block, 0, stream>>>(vel, rWS);
    // T1 = K2+K3+K4, reaches (2,2,2): records1 (ws) -> records4 (d_out raw)
    step_triple<2, 2, 2><<<gridT, block, 0, stream>>>(rWS, rOUT);
    // T2 = K5+K6+K7, reaches (2,3,4): records4 (d_out raw) -> records7 (ws)
    step_triple<2, 3, 4><<<gridT, block, 0, stream>>>(rOUT, rWS);
    // FINAL: records7 (ws) -> planar f32 d_out (overwrites dead records4)
    step_final<<<gridS, block, 0, stream>>>(rWS, out, out + DISP_ELEMS);
}

// Round 22
// 119.534 us; speedup vs baseline: 1.0538x; 1.0514x over previous
//
#include <hip/hip_runtime.h>

// Integrator (scaling & squaring) for vel [16,2,512,512] f32, with logdet-Jacobian.
// ROUND-22 = R17 (best, 120.6us) + interior fast-path in pair kernels:
//   interior tiles (>=32px from image border; 196/256 per image) provably never
//   clamp and never fold weights -> skip clamps/validity (bit-identical).
//   Block-uniform branch; __syncthreads() kept outside branches.
// Structure: INIT (streaming) -> P1=K2K3 (2,2) -> P2=K4K5 (2,2) -> P3=K6K7 (3,4)
//            -> FINAL (streaming ldjac7 + planar f32).
// Records rec_k=(disp_k.y, disp_k.x, ldjac_{k-1}, 0) f16x4; decoupled schedule:
// disp_{k+1} and ldjac_k share one sample position phi(p, disp_k(p)).
// Rotation: init->A(d_out raw), P1:A->B(ws), P2:B->A, P3:A->B, FINAL:B->d_out planar.

#define NB 16
#define HH 512
#define WW 512
#define HW (HH * WW)
#define TOT (NB * HW)
#define EPS 0.0078125f
#define DISP_ELEMS (NB * 2 * HW)
#define SC (512.0f / 511.0f)

typedef _Float16 f16;
typedef _Float16 f16x4 __attribute__((ext_vector_type(4)));

struct SampC {
    int yc0, xc0, yc1, xc1;
    float w00, w01, w10, w11;
};

// general (border-correct) sampler
__device__ __forceinline__ SampC make_sampc(float sy, float sx) {
    float fy = floorf(sy), fx = floorf(sx);
    float wy = sy - fy, wx = sx - fx;
    int y0 = (int)fy, x0 = (int)fx;
    int y1 = y0 + 1, x1 = x0 + 1;
    bool xv0 = (unsigned)x0 < (unsigned)WW;
    bool xv1 = (unsigned)x1 < (unsigned)WW;
    bool yv0 = (unsigned)y0 < (unsigned)HH;
    bool yv1 = (unsigned)y1 < (unsigned)HH;
    SampC s;
    s.xc0 = min(max(x0, 0), WW - 1); s.xc1 = min(max(x1, 0), WW - 1);
    s.yc0 = min(max(y0, 0), HH - 1); s.yc1 = min(max(y1, 0), HH - 1);
    float omwx = 1.0f - wx, omwy = 1.0f - wy;
    s.w00 = (xv0 && yv0) ? omwx * omwy : 0.0f;
    s.w01 = (xv1 && yv0) ? wx * omwy   : 0.0f;
    s.w10 = (xv0 && yv1) ? omwx * wy   : 0.0f;
    s.w11 = (xv1 && yv1) ? wx * wy     : 0.0f;
    return s;
}

// interior sampler: clamps are no-ops, all validity true -> identical values
__device__ __forceinline__ SampC make_sampc_fast(float sy, float sx) {
    float fy = floorf(sy), fx = floorf(sx);
    float wy = sy - fy, wx = sx - fx;
    int y0 = (int)fy, x0 = (int)fx;
    SampC s;
    s.yc0 = y0; s.yc1 = y0 + 1; s.xc0 = x0; s.xc1 = x0 + 1;
    float omwx = 1.0f - wx, omwy = 1.0f - wy;
    s.w00 = omwx * omwy; s.w01 = wx * omwy;
    s.w10 = omwx * wy;   s.w11 = wx * wy;
    return s;
}

__device__ __forceinline__ f16x4 step_rec(f16x4 rv, f16x4 g00, f16x4 g01,
                                          f16x4 g10, f16x4 g11, const SampC& s) {
    float d0 = (float)rv.x, d1 = (float)rv.y, l = (float)rv.z;
    float nd0 = d0 + s.w00 * (float)g00.x + s.w01 * (float)g01.x
                   + s.w10 * (float)g10.x + s.w11 * (float)g11.x;
    float nd1 = d1 + s.w00 * (float)g00.y + s.w01 * (float)g01.y
                   + s.w10 * (float)g10.y + s.w11 * (float)g11.y;
    float nl  = l  + s.w00 * (float)g00.z + s.w01 * (float)g01.z
                   + s.w10 * (float)g10.z + s.w11 * (float)g11.z;
    f16x4 w; w.x = (f16)nd0; w.y = (f16)nd1; w.z = (f16)nl; w.w = (f16)0.0f;
    return w;
}

__device__ __forceinline__ float rnd16(float v) { return (float)(f16)v; }

// block -> (img, tile origin); XCD-pinned: XCD c owns images {2c, 2c+1}.
__device__ __forceinline__ void tile_map(int& img, int& ty0, int& tx0) {
    int bidx = blockIdx.x;
    int xcd = bidx & 7, sub = bidx >> 3;       // sub in [0,512)
    img = 2 * xcd + (sub >= 256 ? 1 : 0);
    int tile = sub & 255;
    tx0 = (tile & 15) << 5;
    ty0 = (tile >> 4) << 5;
}

// XCD-remapped flat index for streaming kernels (16384 blocks).
__device__ __forceinline__ int remap_idx() {
    int bid = blockIdx.x;
    int task = ((bid & 7) << 11) | (bid >> 3);
    return task * 256 + threadIdx.x;
}

// ---------------- INIT (streaming; R15-validated) ----------------
__global__ void __launch_bounds__(256) init_fused(const float* __restrict__ vel,
                                                  f16x4* __restrict__ rdst) {
    int idx = remap_idx();
    int n = idx >> 18;
    int rem = idx & (HW - 1);
    int y = rem >> 9, x = rem & (WW - 1);

    const float* v0 = vel + (size_t)n * 2 * HW;
    const float* v1 = v0 + HW;

    int ym = max(y - 1, 0), yp = min(y + 1, HH - 1);
    int xm = max(x - 1, 0), xp = min(x + 1, WW - 1);
    int r0 = ym * WW, r1 = y * WW, r2 = yp * WW;

    float A00 = v0[r0 + xm], A01 = v0[r0 + x], A02 = v0[r0 + xp];
    float A10 = v0[r1 + xm], A11 = v0[r1 + x], A12 = v0[r1 + xp];
    float A20 = v0[r2 + xm], A21 = v0[r2 + x], A22 = v0[r2 + xp];
    float B00 = v1[r0 + xm], B01 = v1[r0 + x], B02 = v1[r0 + xp];
    float B10 = v1[r1 + xm], B11 = v1[r1 + x], B12 = v1[r1 + xp];
    float B20 = v1[r2 + xm], B21 = v1[r2 + x], B22 = v1[r2 + xp];

    float a = 0.125f * ((A20 + 2.0f * A21 + A22) - (A00 + 2.0f * A01 + A02));
    float b = 0.125f * ((A02 + 2.0f * A12 + A22) - (A00 + 2.0f * A10 + A20));
    float c = 0.125f * ((B20 + 2.0f * B21 + B22) - (B00 + 2.0f * B01 + B02));
    float d = 0.125f * ((B02 + 2.0f * B12 + B22) - (B00 + 2.0f * B10 + B20));

    float xa = a, xb = b, xc = c, xd = d;
    float ld = EPS * (xa + xd);
    float na = xa * a + xb * c, nb = xa * b + xb * d;
    float nc = xc * a + xd * c, nd = xc * b + xd * d;
    xa = na; xb = nb; xc = nc; xd = nd;
    ld -= (EPS * EPS) * (xa + xd) * 0.5f;
    na = xa * a + xb * c; nb = xa * b + xb * d;
    nc = xc * a + xd * c; nd = xc * b + xd * d;
    xa = na; xb = nb; xc = nc; xd = nd;
    ld += (EPS * EPS * EPS) * (xa + xd) * (1.0f / 3.0f);
    na = xa * a + xb * c;
    nd = xc * b + xd * d;
    ld -= (EPS * EPS * EPS * EPS) * (na + nd) * 0.25f;

    float d0 = rnd16(EPS * A11);
    float d1 = rnd16(EPS * B11);

    float sy = fmaf((float)y + d0, SC, -0.5f);
    float sx = fmaf((float)x + d1, SC, -0.5f);
    SampC s = make_sampc(sy, sx);

    bool rlo = (sy < (float)y);
    bool clo = (sx < (float)x);

    float Ar0c0 = rlo ? A00 : A10, Ar0c1 = rlo ? A01 : A11, Ar0c2 = rlo ? A02 : A12;
    float Ar1c0 = rlo ? A10 : A20, Ar1c1 = rlo ? A11 : A21, Ar1c2 = rlo ? A12 : A22;
    float Br0c0 = rlo ? B00 : B10, Br0c1 = rlo ? B01 : B11, Br0c2 = rlo ? B02 : B12;
    float Br1c0 = rlo ? B10 : B20, Br1c1 = rlo ? B11 : B21, Br1c2 = rlo ? B12 : B22;

    float g00x = rnd16(EPS * (clo ? Ar0c0 : Ar0c1));
    float g01x = rnd16(EPS * (clo ? Ar0c1 : Ar0c2));
    float g10x = rnd16(EPS * (clo ? Ar1c0 : Ar1c1));
    float g11x = rnd16(EPS * (clo ? Ar1c1 : Ar1c2));
    float g00y = rnd16(EPS * (clo ? Br0c0 : Br0c1));
    float g01y = rnd16(EPS * (clo ? Br0c1 : Br0c2));
    float g10y = rnd16(EPS * (clo ? Br1c0 : Br1c1));
    float g11y = rnd16(EPS * (clo ? Br1c1 : Br1c2));

    float nd0 = d0 + s.w00 * g00x + s.w01 * g01x + s.w10 * g10x + s.w11 * g11x;
    float nd1 = d1 + s.w00 * g00y + s.w01 * g01y + s.w10 * g10y + s.w11 * g11y;

    f16x4 rec;
    rec.x = (f16)nd0; rec.y = (f16)nd1; rec.z = (f16)ld; rec.w = (f16)0.0f;
    rdst[(size_t)n * HW + rem] = rec;
}

// ---------------- STEP-PAIR with interior fast path ----------------
// Core 32x32; R1/R2 per-step reaches (R17-validated). Interior tiles
// (>=32px from image border) skip clamps/validity — bit-identical.
template <int R1, int R2>
__global__ void __launch_bounds__(256, 4) step_pair(const f16x4* __restrict__ rsrc,
                                                    f16x4* __restrict__ rdst) {
    constexpr int MW = 32 + 2 * R2;
    constexpr int EW = 32 + 2 * (R1 + R2);
    __shared__ f16x4 IN[EW][EW + 1];
    __shared__ f16x4 MID[MW][MW + 1];

    int img, ty0, tx0;
    tile_map(img, ty0, tx0);
    int t = threadIdx.x;
    const f16x4* rp = rsrc + (size_t)img * HW;

    const int oyE = ty0 - (R1 + R2), oxE = tx0 - (R1 + R2);
    const int oyM = ty0 - R2,        oxM = tx0 - R2;
    bool safe = (tx0 >= 32) && (tx0 <= 448) && (ty0 >= 32) && (ty0 <= 448);

    // phase 0: load ext tile
    if (safe) {
        for (int i = t; i < EW * EW; i += 256) {
            int ey = i / EW, ex = i - ey * EW;
            IN[ey][ex] = rp[(oyE + ey) * WW + (oxE + ex)];
        }
    } else {
        for (int i = t; i < EW * EW; i += 256) {
            int ey = i / EW, ex = i - ey * EW;
            int gy = min(max(oyE + ey, 0), HH - 1);
            int gx = min(max(oxE + ex, 0), WW - 1);
            IN[ey][ex] = rp[gy * WW + gx];
        }
    }
    __syncthreads();

    // phase 1: step a on core+R2, gathers reach R1 in IN
    if (safe) {
        for (int i = t; i < MW * MW; i += 256) {
            int my = i / MW, mx = i - my * MW;
            int qy = oyM + my, qx = oxM + mx;
            f16x4 rv = IN[my + R1][mx + R1];
            float sy = fmaf((float)qy + (float)rv.x, SC, -0.5f);
            float sx = fmaf((float)qx + (float)rv.y, SC, -0.5f);
            SampC s = make_sampc_fast(sy, sx);
            f16x4 g00 = IN[s.yc0 - oyE][s.xc0 - oxE];
            f16x4 g01 = IN[s.yc0 - oyE][s.xc1 - oxE];
            f16x4 g10 = IN[s.yc1 - oyE][s.xc0 - oxE];
            f16x4 g11 = IN[s.yc1 - oyE][s.xc1 - oxE];
            MID[my][mx] = step_rec(rv, g00, g01, g10, g11, s);
        }
    } else {
        for (int i = t; i < MW * MW; i += 256) {
            int my = i / MW, mx = i - my * MW;
            int qy = oyM + my, qx = oxM + mx;
            f16x4 rv = IN[my + R1][mx + R1];
            float sy = fmaf((float)qy + (float)rv.x, SC, -0.5f);
            float sx = fmaf((float)qx + (float)rv.y, SC, -0.5f);
            SampC s = make_sampc(sy, sx);
            f16x4 g00 = IN[s.yc0 - oyE][s.xc0 - oxE];
            f16x4 g01 = IN[s.yc0 - oyE][s.xc1 - oxE];
            f16x4 g10 = IN[s.yc1 - oyE][s.xc0 - oxE];
            f16x4 g11 = IN[s.yc1 - oyE][s.xc1 - oxE];
            MID[my][mx] = step_rec(rv, g00, g01, g10, g11, s);
        }
    }
    __syncthreads();

    // phase 2: step b on core, gathers reach R2 in MID, write global
    f16x4* wp = rdst + (size_t)img * HW;
    if (safe) {
        for (int i = t; i < 1024; i += 256) {
            int cy = i >> 5, cx = i & 31;
            int qy = ty0 + cy, qx = tx0 + cx;
            f16x4 rv = MID[cy + R2][cx + R2];
            float sy = fmaf((float)qy + (float)rv.x, SC, -0.5f);
            float sx = fmaf((float)qx + (float)rv.y, SC, -0.5f);
            SampC s = make_sampc_fast(sy, sx);
            f16x4 g00 = MID[s.yc0 - oyM][s.xc0 - oxM];
            f16x4 g01 = MID[s.yc0 - oyM][s.xc1 - oxM];
            f16x4 g10 = MID[s.yc1 - oyM][s.xc0 - oxM];
            f16x4 g11 = MID[s.yc1 - oyM][s.xc1 - oxM];
            wp[qy * WW + qx] = step_rec(rv, g00, g01, g10, g11, s);
        }
    } else {
        for (int i = t; i < 1024; i += 256) {
            int cy = i >> 5, cx = i & 31;
            int qy = ty0 + cy, qx = tx0 + cx;
            f16x4 rv = MID[cy + R2][cx + R2];
            float sy = fmaf((float)qy + (float)rv.x, SC, -0.5f);
            float sx = fmaf((float)qx + (float)rv.y, SC, -0.5f);
            SampC s = make_sampc(sy, sx);
            f16x4 g00 = MID[s.yc0 - oyM][s.xc0 - oxM];
            f16x4 g01 = MID[s.yc0 - oyM][s.xc1 - oxM];
            f16x4 g10 = MID[s.yc1 - oyM][s.xc0 - oxM];
            f16x4 g11 = MID[s.yc1 - oyM][s.xc1 - oxM];
            wp[qy * WW + qx] = step_rec(rv, g00, g01, g10, g11, s);
        }
    }
}

// ---------------- FINAL: streaming ldjac7 + planar f32 output ----------------
__global__ void __launch_bounds__(256) step_final(const f16x4* __restrict__ rsrc,
                                                  float* __restrict__ doutp,
                                                  float* __restrict__ loutp) {
    int idx = remap_idx();
    int n = idx >> 18;
    int rem = idx & (HW - 1);
    int y = rem >> 9, x = rem & (WW - 1);

    const f16x4* rp = rsrc + (size_t)n * HW;

    f16x4 rv = rp[rem];
    float d0 = (float)rv.x, d1 = (float)rv.y, l = (float)rv.z;

    float sy = fmaf((float)y + d0, SC, -0.5f);
    float sx = fmaf((float)x + d1, SC, -0.5f);
    SampC s = make_sampc(sy, sx);

    f16x4 g00 = rp[s.yc0 * WW + s.xc0], g01 = rp[s.yc0 * WW + s.xc1];
    f16x4 g10 = rp[s.yc1 * WW + s.xc0], g11 = rp[s.yc1 * WW + s.xc1];

    float nl = l + s.w00 * (float)g00.z + s.w01 * (float)g01.z
                 + s.w10 * (float)g10.z + s.w11 * (float)g11.z;

    float* pd = doutp + (size_t)n * 2 * HW;
    pd[rem]      = d0;
    pd[HW + rem] = d1;
    loutp[(size_t)n * HW + rem] = nl;
}

extern "C" void kernel_launch(void* const* d_in, const int* in_sizes, int n_in,
                              void* d_out, int out_size, void* d_ws, size_t ws_size,
                              hipStream_t stream) {
    const float* vel = (const float*)d_in[0];
    float* out = (float*)d_out;

    f16x4* rA = (f16x4*)d_out;   // raw record scratch (32MB of 48MB)
    f16x4* rB = (f16x4*)d_ws;    // raw record scratch (32MB of 48MB)

    dim3 block(256), gridT(4096), gridS(TOT / 256);

    // INIT -> A (records1)
    init_fused<<<gridS, block, 0, stream>>>(vel, rA);
    // P1 = (K2,K3): A -> B   reaches 2/2
    step_pair<2, 2><<<gridT, block, 0, stream>>>(rA, rB);
    // P2 = (K4,K5): B -> A   reaches 2/2
    step_pair<2, 2><<<gridT, block, 0, stream>>>(rB, rA);
    // P3 = (K6,K7): A -> B   reaches 3/4
    step_pair<3, 4><<<gridT, block, 0, stream>>>(rA, rB);
    // FINAL: B -> d_out planar (disp7 f32, ldjac7 f32); B=ws so no aliasing
    step_final<<<gridS, block, 0, stream>>>(rB, out, out + DISP_ELEMS);
}